// Round 8
// baseline (10220.876 us; speedup 1.0000x reference)
//
#include <hip/hip_runtime.h>
#include <stdint.h>

typedef _Float16 half8 __attribute__((ext_vector_type(8)));
typedef _Float16 h2    __attribute__((ext_vector_type(2)));
typedef float    f32x4 __attribute__((ext_vector_type(4)));
typedef uint32_t u4    __attribute__((ext_vector_type(4)));

__device__ __forceinline__ float dot2(uint32_t a, uint32_t b, float c) {
    return __builtin_amdgcn_fdot2(__builtin_bit_cast(h2, a),
                                  __builtin_bit_cast(h2, b), c, false);
}

// tanh(z) = 1 - 2/(exp(2z)+1)
__device__ __forceinline__ float fast_tanh(float z) {
    float e = __expf(2.0f * z);
    return 1.0f - 2.0f * __builtin_amdgcn_rcpf(e + 1.0f);
}

#define TT 4096
#define NB 32
#define HD 512
#define KK 16              // kk-steps: K=512, 32 per step
#define DL 6               // dot2 kk-steps whose W lives in LDS (kk 0..5)
#define DR (KK - DL)       // dot2 kk-steps in registers (10)

// One block per batch row; 512 threads (8 waves). HYBRID: MFMA pipe (per-CU,
// 3377 FLOP/cyc) and VALU pipe (1024 FLOP/cyc/CU via dot2) run CONCURRENTLY
// on disjoint column halves. Every wave does both roles (mapping-robust):
//   - MFMA: wave w owns cols [w*32, w*32+32) as 2 col-tiles; B-frags fully
//     register-resident (128 words). Fragment packing byte-identical to the
//     round-7 kernel (passed, absmax = fp16 floor).
//   - dot2: thread owns cols 256+w*32+2*lc+{0,1} over the A-FRAGMENT k-order
//     (lg owns k in {kk*32+lg*8 .. +7}) -> the SAME per-kk broadcast b128
//     serves the MFMA A-frag and the dot2 scalar pairs. 4-way lg-reduce via
//     pads[4][256]. W: 80 words reg + 48 words LDS (12 b128/thread/step).
// Register W total = 208 words (round-2-proven allocation).
// Out-stores deferred one step so their vmcnt drain hides under the dot phase.
__global__ __launch_bounds__(512, 1)
void esn_kernel(const float* __restrict__ X, const float* __restrict__ W_in,
                const float* __restrict__ W_int, const float* __restrict__ noise,
                float* __restrict__ out)
{
    __shared__ __align__(16) _Float16 s_buf[2][HD];   // 2 KB state (fp16, dbuf)
    __shared__ float pads[4][256];                    // 4 KB dot2 partials
    __shared__ u4 wstash[8 * DL * 2 * 64];            // 96 KB dot2-W LDS part
    __shared__ float win_lds[HD][3];                  // 6 KB input weights

    const int tid = threadIdx.x;
    const int b   = blockIdx.x;
    const int w   = tid >> 6;      // wave 0..7
    const int l   = tid & 63;      // lane
    const int lg  = l >> 4;        // k-subgroup 0..3
    const int lc  = l & 15;        // col-in-tile 0..15

    win_lds[tid][0] = W_in[tid*3 + 0];
    win_lds[tid][1] = W_in[tid*3 + 1];
    win_lds[tid][2] = W_in[tid*3 + 2];

    // ---- Prologue: pack W_int (fp32 [k][h]) ----
    // MFMA B-frags (round-7 recipe, CT=2): lane l slot j ->
    //   W_int[kk*32 + lg*8 + j][w*32 + ct*16 + lc]
    half8 wregB[2][KK];                 // 128 words
    #pragma unroll
    for (int ct = 0; ct < 2; ++ct) {
        const int col = w*32 + ct*16 + lc;
        #pragma unroll
        for (int kk = 0; kk < KK; ++kk) {
            const int kb = kk*32 + lg*8;
            half8 hb;
            #pragma unroll
            for (int j = 0; j < 8; ++j)
                hb[j] = (_Float16)W_int[(size_t)(kb + j)*HD + col];
            wregB[ct][kk] = hb;
        }
    }
    // dot2 W (A-frag k-order): pair j2 of kk -> k = kk*32+lg*8+2*j2
    u4 wregD[2][DR];                    // 80 words
    #pragma unroll
    for (int c = 0; c < 2; ++c) {
        const int col = 256 + w*32 + 2*lc + c;
        #pragma unroll
        for (int kk = 0; kk < KK; ++kk) {
            u4 q;
            #pragma unroll
            for (int j2 = 0; j2 < 4; ++j2) {
                const int k = kk*32 + lg*8 + 2*j2;
                h2 hp;
                hp[0] = (_Float16)W_int[(size_t)k*HD + col];
                hp[1] = (_Float16)W_int[(size_t)(k+1)*HD + col];
                q[j2] = __builtin_bit_cast(uint32_t, hp);
            }
            if (kk < DL) wstash[((w*DL + kk)*2 + c)*64 + l] = q;
            else         wregD[c][kk - DL] = q;
        }
    }
    s_buf[0][tid] = (_Float16)0.01f;    // prev0 = 0.01 (512 threads = HD)
    __syncthreads();

    const float* Xb   = X   + (size_t)b * TT * 3;
    float*       outb = out + (size_t)b * TT * HD;

    float om0 = 0.f, om1 = 0.f, od = 0.f;   // deferred out values
    int cur = 0;
    for (int t = 0; t < TT; ++t) {
        // ---- step top: flush step t-1 outputs (drain hides under dot) ----
        if (t > 0) {
            if (l < 16) {
                float* op = outb + (size_t)(t-1)*HD + w*32 + l;
                op[0] = om0; op[16] = om1;
            }
            if (tid < 256) outb[(size_t)(t-1)*HD + 256 + tid] = od;
        }
        // this step's noise / input (consumed in epilogue)
        float nzm0 = 0.f, nzm1 = 0.f, nzd = 0.f;
        if (l < 16) {
            const float* np = noise + ((size_t)t*NB + b)*HD + w*32 + l;
            nzm0 = np[0]; nzm1 = np[16];
        }
        if (tid < 256) nzd = noise[((size_t)t*NB + b)*HD + 256 + tid];
        const float x0 = Xb[t*3 + 0];
        const float x1 = Xb[t*3 + 1];
        const float x2 = Xb[t*3 + 2];

        // ---- fused MFMA + dot2 phase over 16 kk-steps ----
        const u4* sb4 = (const u4*)(&s_buf[cur][0]);
        f32x4 acc0{}, acc1{};
        float d0a = 0.f, d0b = 0.f, d1a = 0.f, d1b = 0.f;
        #pragma unroll
        for (int kk = 0; kk < KK; ++kk) {
            const u4 sq = sb4[kk*4 + lg];        // ONE bcast b128: A-frag + dot2 scalars
            const half8 af = __builtin_bit_cast(half8, sq);
            acc0 = __builtin_amdgcn_mfma_f32_16x16x32_f16(af, wregB[0][kk], acc0, 0, 0, 0);
            acc1 = __builtin_amdgcn_mfma_f32_16x16x32_f16(af, wregB[1][kk], acc1, 0, 0, 0);
            u4 wq0, wq1;
            if (kk < DL) {
                wq0 = wstash[((w*DL + kk)*2 + 0)*64 + l];
                wq1 = wstash[((w*DL + kk)*2 + 1)*64 + l];
            } else {
                wq0 = wregD[0][kk - DL];
                wq1 = wregD[1][kk - DL];
            }
            if (kk & 1) {
                #pragma unroll
                for (int j2 = 0; j2 < 4; ++j2) {
                    d0b = dot2(sq[j2], wq0[j2], d0b);
                    d1b = dot2(sq[j2], wq1[j2], d1b);
                }
            } else {
                #pragma unroll
                for (int j2 = 0; j2 < 4; ++j2) {
                    d0a = dot2(sq[j2], wq0[j2], d0a);
                    d1a = dot2(sq[j2], wq1[j2], d1a);
                }
            }
        }
        // dot2 partials -> pads (one b64 per thread)
        *(float2*)&pads[lg][w*32 + 2*lc] = make_float2(d0a + d0b, d1a + d1b);
        __syncthreads();

        // ---- epilogue ----
        if (l < 16) {                       // MFMA cols: w*32 + l, +16
            const int c0 = w*32 + l;
            float z0 = acc0[0] + win_lds[c0   ][0]*x0 + win_lds[c0   ][1]*x1 + win_lds[c0   ][2]*x2 + 0.01f*nzm0;
            float z1 = acc1[0] + win_lds[c0+16][0]*x0 + win_lds[c0+16][1]*x1 + win_lds[c0+16][2]*x2 + 0.01f*nzm1;
            om0 = fast_tanh(z0);
            om1 = fast_tanh(z1);
            s_buf[cur^1][c0     ] = (_Float16)om0;
            s_buf[cur^1][c0 + 16] = (_Float16)om1;
        }
        if (tid < 256) {                    // dot2 col: 256 + tid
            const int col = 256 + tid;
            float z = pads[0][tid] + pads[1][tid] + pads[2][tid] + pads[3][tid]
                    + win_lds[col][0]*x0 + win_lds[col][1]*x1 + win_lds[col][2]*x2 + 0.01f*nzd;
            od = fast_tanh(z);
            s_buf[cur^1][col] = (_Float16)od;
        }
        __syncthreads();
        cur ^= 1;
    }
    // flush final step
    if (l < 16) {
        float* op = outb + (size_t)(TT-1)*HD + w*32 + l;
        op[0] = om0; op[16] = om1;
    }
    if (tid < 256) outb[(size_t)(TT-1)*HD + 256 + tid] = od;
}

extern "C" void kernel_launch(void* const* d_in, const int* in_sizes, int n_in,
                              void* d_out, int out_size, void* d_ws, size_t ws_size,
                              hipStream_t stream)
{
    const float* X     = (const float*)d_in[0];
    const float* W_in  = (const float*)d_in[1];
    const float* W_int = (const float*)d_in[2];
    const float* noise = (const float*)d_in[3];
    float* out = (float*)d_out;

    esn_kernel<<<dim3(NB), dim3(512), 0, stream>>>(X, W_in, W_int, noise, out);
}